// Round 7
// baseline (202.464 us; speedup 1.0000x reference)
//
#include <hip/hip_runtime.h>

// CTC loss forward, B=64 T=1000 V=64 L=150 (S=2L+1=301) — single fused kernel.
// Per block (one example): wave0 = alpha fwd t=0..mid, wave1 = beta bwd t=tf..mid+1,
// wave2 = per-frame lse sum (finishes early, hidden under recursion).
// Exp-domain fp64 state; emissions prefetched via pinned inline-asm global loads
// (40/chunk), counted s_waitcnt vmcnt(40) so one chunk is always in flight.

#define VV 64
#define L2E 1.4426950408889634f
#define LN2D 0.6931471805599453
#define CH 8

template <int IMM>
__device__ __forceinline__ float gload(const float* p) {
    float r;
    asm volatile("global_load_dword %0, %1, off offset:%2"
                 : "=v"(r) : "v"(p), "n"(IMM));
    return r;
}

#define ISSUE5(E, K, IMM)                                                       \
    do {                                                                        \
        E[0][K] = gload<IMM>(ap0); E[1][K] = gload<IMM>(ap1);                   \
        E[2][K] = gload<IMM>(ap2); E[3][K] = gload<IMM>(ap3);                   \
        E[4][K] = gload<IMM>(ap4);                                              \
    } while (0)

#define ISSUEF(E)                                                               \
    do { ISSUE5(E,0,0);    ISSUE5(E,1,256);  ISSUE5(E,2,512);  ISSUE5(E,3,768); \
         ISSUE5(E,4,1024); ISSUE5(E,5,1280); ISSUE5(E,6,1536); ISSUE5(E,7,1792);} while (0)

#define ISSUEB(E)                                                               \
    do { ISSUE5(E,0,0);     ISSUE5(E,1,-256);  ISSUE5(E,2,-512);  ISSUE5(E,3,-768); \
         ISSUE5(E,4,-1024); ISSUE5(E,5,-1280); ISSUE5(E,6,-1536); ISSUE5(E,7,-1792);} while (0)

#define SETAPF(CB)                                                              \
    do { int cb_ = (CB); if (cb_ > tf - 7) cb_ = tf - 7; if (cb_ < 0) cb_ = 0;  \
         const float* fr_ = lg + ((size_t)cb_ << 6);                            \
         ap0 = fr_ + sym[0]; ap1 = fr_ + sym[1]; ap2 = fr_ + sym[2];            \
         ap3 = fr_ + sym[3]; ap4 = fr_ + sym[4]; } while (0)

#define SETAPB(CB)                                                              \
    do { int cb_ = (CB); if (cb_ < 7) cb_ = 7; if (cb_ > tf) cb_ = tf;          \
         const float* fr_ = lg + ((size_t)cb_ << 6);                            \
         ap0 = fr_ + sym[0]; ap1 = fr_ + sym[1]; ap2 = fr_ + sym[2];            \
         ap3 = fr_ + sym[3]; ap4 = fr_ + sym[4]; } while (0)

#define WAITCNT                                                                 \
    do { asm volatile("s_waitcnt vmcnt(40)" ::: "memory");                      \
         __builtin_amdgcn_sched_barrier(0); } while (0)

#define CONV(E)                                                                 \
    do {                                                                        \
        _Pragma("unroll")                                                       \
        for (int i_ = 0; i_ < 5; ++i_) {                                        \
            _Pragma("unroll")                                                   \
            for (int k_ = 0; k_ < CH; ++k_)                                     \
                E[i_][k_] = __builtin_amdgcn_exp2f(E[i_][k_] * L2E);            \
        }                                                                       \
    } while (0)

#define PROCF(E, STEP0, MASKED)                                                 \
    do {                                                                        \
        _Pragma("unroll")                                                       \
        for (int k_ = 0; k_ < CH; ++k_) {                                       \
            double a_ = __shfl_up(p[4], 1);                                     \
            double b_ = __shfl_up(p[3], 1);                                     \
            if (lane == 0) { a_ = 0.0; b_ = 0.0; }                              \
            double e_[5];                                                       \
            _Pragma("unroll")                                                   \
            for (int i_ = 0; i_ < 5; ++i_) e_[i_] = (double)E[i_][k_];          \
            double n0_ = e_[0] * (p[0] + a_ + skd[0] * b_);                     \
            double n1_ = e_[1] * (p[1] + p[0] + skd[1] * a_);                   \
            double n2_ = e_[2] * (p[2] + p[1] + skd[2] * p[0]);                 \
            double n3_ = e_[3] * (p[3] + p[2] + skd[3] * p[1]);                 \
            double n4_ = e_[4] * (p[4] + p[3] + skd[4] * p[2]);                 \
            if (MASKED) {                                                       \
                bool act_ = ((STEP0) + k_) < nst_;                              \
                p[0] = act_ ? n0_ : p[0]; p[1] = act_ ? n1_ : p[1];             \
                p[2] = act_ ? n2_ : p[2]; p[3] = act_ ? n3_ : p[3];             \
                p[4] = act_ ? n4_ : p[4];                                       \
            } else {                                                            \
                p[0] = n0_; p[1] = n1_; p[2] = n2_; p[3] = n3_; p[4] = n4_;     \
            }                                                                   \
        }                                                                       \
    } while (0)

#define PROCB(E, STEP0, MASKED)                                                 \
    do {                                                                        \
        _Pragma("unroll")                                                       \
        for (int k_ = 0; k_ < CH; ++k_) {                                       \
            double pn0_ = __shfl_down(p[0], 1);                                 \
            double pn1_ = __shfl_down(p[1], 1);                                 \
            float en0_ = __shfl_down(E[0][k_], 1);                              \
            float en1_ = __shfl_down(E[1][k_], 1);                              \
            if (lane == 63) { pn0_ = 0.0; pn1_ = 0.0; }                         \
            double u_[5];                                                       \
            _Pragma("unroll")                                                   \
            for (int i_ = 0; i_ < 5; ++i_) u_[i_] = p[i_] * (double)E[i_][k_];  \
            double u5_ = pn0_ * (double)en0_;                                   \
            double u6_ = pn1_ * (double)en1_;                                   \
            double n0_ = u_[0] + u_[1] + skd[2] * u_[2];                        \
            double n1_ = u_[1] + u_[2] + skd[3] * u_[3];                        \
            double n2_ = u_[2] + u_[3] + skd[4] * u_[4];                        \
            double n3_ = u_[3] + u_[4] + skd[5] * u5_;                          \
            double n4_ = u_[4] + u5_ + skd[6] * u6_;                            \
            if (MASKED) {                                                       \
                bool act_ = ((STEP0) + k_) < nst_;                              \
                p[0] = act_ ? n0_ : p[0]; p[1] = act_ ? n1_ : p[1];             \
                p[2] = act_ ? n2_ : p[2]; p[3] = act_ ? n3_ : p[3];             \
                p[4] = act_ ? n4_ : p[4];                                       \
            } else {                                                            \
                p[0] = n0_; p[1] = n1_; p[2] = n2_; p[3] = n3_; p[4] = n4_;     \
            }                                                                   \
        }                                                                       \
    } while (0)

#define RENORM()                                                                \
    do {                                                                        \
        double mx_ = fmax(fmax(fmax(p[0], p[1]), fmax(p[2], p[3])), p[4]);      \
        int ex_ = (__double2hiint(mx_) >> 20) & 0x7ff;                          \
        _Pragma("unroll")                                                       \
        for (int o_ = 32; o_ >= 1; o_ >>= 1) {                                  \
            int t_ = __shfl_xor(ex_, o_);                                       \
            ex_ = t_ > ex_ ? t_ : ex_;                                          \
        }                                                                       \
        if (ex_ > 0) {                                                          \
            Cexp += ex_ - 1023;                                                 \
            double r_ = __hiloint2double((2046 - ex_) << 20, 0);                \
            _Pragma("unroll")                                                   \
            for (int i_ = 0; i_ < 5; ++i_) p[i_] *= r_;                         \
        }                                                                       \
    } while (0)

__global__ __launch_bounds__(192, 1) void ctc_kernel(const float* __restrict__ lgall,
                                                     const int* __restrict__ audio_len,
                                                     const int* __restrict__ labels,
                                                     float* __restrict__ out,
                                                     int B, int T, int L) {
    const int b = blockIdx.x;
    const int tid = threadIdx.x;
    const int lane = tid & 63;
    const int wid = tid >> 6;
    const int S = 2 * L + 1;
    const float* lg = lgall + (size_t)b * T * VV;

    int al = audio_len[b];
    int Tb = ((al + 128) >> 7) >> 1;
    if (Tb < 1) Tb = 1;
    if (Tb > T) Tb = T;
    const int tf = Tb - 1;
    const int mid = tf >> 1;   // fwd steps: frames 1..mid ; bwd: frames tf..mid+1

    __shared__ int lab_sh[152];
    __shared__ double beta_sh[324];
    __shared__ double sumlse_sh;
    __shared__ int cexpb_sh;

    for (int k = tid; k < L; k += 192) lab_sh[k] = labels[b * L + k];
    __syncthreads();

    int cnt = 0;
    for (int k = lane; k < L; k += 64) cnt += (lab_sh[k] >= 0) ? 1 : 0;
    #pragma unroll
    for (int off = 32; off >= 1; off >>= 1) cnt += __shfl_xor(cnt, off);
    const int s_last = 2 * cnt;

    // per-state symbols (states 5*lane+i) and skip flags (i up to 6 for bwd)
    int sym[5];
    double skd[7];
    #pragma unroll
    for (int i = 0; i < 7; ++i) {
        int s = lane * 5 + i;
        int sy = 0;
        double sk = 0.0;
        if (s < S && (s & 1)) {
            int lv = lab_sh[s >> 1];
            sy = lv < 0 ? 0 : lv;
            if (s >= 3 && sy != 0) {
                int lv2 = lab_sh[(s >> 1) - 1];
                int s2 = lv2 < 0 ? 0 : lv2;
                sk = (sy != s2) ? 1.0 : 0.0;
            }
        }
        if (i < 5) sym[i] = sy;
        skd[i] = sk;
    }

    double p[5];
    int Cexp = 0;

    if (wid == 0) {
        // ---------------- forward: alpha ----------------
        #pragma unroll
        for (int i = 0; i < 5; ++i) {
            float x = lg[sym[i]];
            int s = lane * 5 + i;
            p[i] = (s <= 1) ? (double)__builtin_amdgcn_exp2f(x * L2E) : 0.0;
        }
        const int nst_ = mid;
        if (nst_ > 0) {
            const int nch = (nst_ + CH - 1) / CH;
            float eA[5][CH], eB[5][CH];
            const float *ap0, *ap1, *ap2, *ap3, *ap4;
            SETAPF(1);      ISSUEF(eA);
            SETAPF(1 + CH); ISSUEF(eB);
            int c = 0, step0 = 0, cbn = 1 + 2 * CH;
            for (;;) {
                WAITCNT; CONV(eA);
                if (c == nch - 1) { PROCF(eA, step0, 1); break; }
                PROCF(eA, step0, 0);
                SETAPF(cbn); ISSUEF(eA); cbn += CH;
                ++c; step0 += CH;
                if ((c & 3) == 0) RENORM();
                WAITCNT; CONV(eB);
                if (c == nch - 1) { PROCF(eB, step0, 1); break; }
                PROCF(eB, step0, 0);
                SETAPF(cbn); ISSUEF(eB); cbn += CH;
                ++c; step0 += CH;
                if ((c & 3) == 0) RENORM();
            }
        }
        RENORM();   // keep magnitudes safe for the dot product
    } else if (wid == 1) {
        // ---------------- backward: beta ----------------
        #pragma unroll
        for (int i = 0; i < 5; ++i) {
            int s = lane * 5 + i;
            p[i] = (s == s_last || s == s_last - 1) ? 1.0 : 0.0;
        }
        const int nst_ = tf - mid;
        if (nst_ > 0) {
            const int nch = (nst_ + CH - 1) / CH;
            float eA[5][CH], eB[5][CH];
            const float *ap0, *ap1, *ap2, *ap3, *ap4;
            SETAPB(tf);      ISSUEB(eA);
            SETAPB(tf - CH); ISSUEB(eB);
            int c = 0, step0 = 0, cbn = tf - 2 * CH;
            for (;;) {
                WAITCNT; CONV(eA);
                if (c == nch - 1) { PROCB(eA, step0, 1); break; }
                PROCB(eA, step0, 0);
                SETAPB(cbn); ISSUEB(eA); cbn -= CH;
                ++c; step0 += CH;
                if ((c & 3) == 0) RENORM();
                WAITCNT; CONV(eB);
                if (c == nch - 1) { PROCB(eB, step0, 1); break; }
                PROCB(eB, step0, 0);
                SETAPB(cbn); ISSUEB(eB); cbn -= CH;
                ++c; step0 += CH;
                if ((c & 3) == 0) RENORM();
            }
        }
        RENORM();
        #pragma unroll
        for (int i = 0; i < 5; ++i) beta_sh[lane * 5 + i] = p[i];
        if (lane == 0) cexpb_sh = Cexp;
    } else {
        // ---------------- lse wave: sum of per-frame logsumexp ----------------
        const float4* lg4 = (const float4*)lg;
        const int q = lane & 15;
        const int fg = lane >> 4;
        double acc = 0.0;
        for (int g0 = 0; g0 * 4 < Tb; ++g0) {
            int t = g0 * 4 + fg;
            double v = 0.0;
            if (t < Tb) {
                float4 x = lg4[t * 16 + q];
                float m = fmaxf(fmaxf(x.x, x.y), fmaxf(x.z, x.w));
                #pragma unroll
                for (int off = 8; off >= 1; off >>= 1) m = fmaxf(m, __shfl_xor(m, off));
                float s = __expf(x.x - m) + __expf(x.y - m) + __expf(x.z - m) + __expf(x.w - m);
                #pragma unroll
                for (int off = 8; off >= 1; off >>= 1) s += __shfl_xor(s, off);
                v = (double)(m + __logf(s));
            }
            if (q == 0) acc += v;
        }
        #pragma unroll
        for (int o = 32; o >= 1; o >>= 1) acc += __shfl_xor(acc, o);
        if (lane == 0) sumlse_sh = acc;
    }
    __syncthreads();

    if (wid == 0) {
        double dot = 0.0;
        #pragma unroll
        for (int i = 0; i < 5; ++i) dot += p[i] * beta_sh[lane * 5 + i];
        #pragma unroll
        for (int o = 32; o >= 1; o >>= 1) dot += __shfl_xor(dot, o);
        if (lane == 0) {
            dot = fmax(dot, 1e-290);
            double lp = log(dot) + (double)(Cexp + cexpb_sh) * LN2D - sumlse_sh;
            atomicAdd(out, (float)(-lp / (double)B));
        }
    }
}

extern "C" void kernel_launch(void* const* d_in, const int* in_sizes, int n_in,
                              void* d_out, int out_size, void* d_ws, size_t ws_size,
                              hipStream_t stream) {
    const float* logits = (const float*)d_in[0];
    const int* audio = (const int*)d_in[1];
    const int* labels = (const int*)d_in[2];
    float* out = (float*)d_out;

    int B = in_sizes[1];
    int L = in_sizes[2] / B;
    int T = in_sizes[0] / (B * VV);

    hipMemsetAsync(out, 0, sizeof(float), stream);
    ctc_kernel<<<B, 192, 0, stream>>>(logits, audio, labels, out, B, T, L);
}

// Round 8
// 140.342 us; speedup vs baseline: 1.4426x; 1.4426x over previous
//
#include <hip/hip_runtime.h>

// CTC loss forward, B=64 T=1000 V=64 L=150 (S=2L+1=301) — single fused kernel.
// Per block (one example): wave0 = alpha fwd t=0..mid, wave1 = beta bwd t=tf..mid+1,
// waves 2-5 = per-frame lse sum split 4 ways (software-pipelined, hidden under recursion).
// Exp-domain fp64 state; emissions prefetched via pinned inline-asm global loads
// (40/chunk), counted s_waitcnt vmcnt(40) so one chunk is always in flight.

#define VV 64
#define L2E 1.4426950408889634f
#define LN2D 0.6931471805599453
#define CH 8

template <int IMM>
__device__ __forceinline__ float gload(const float* p) {
    float r;
    asm volatile("global_load_dword %0, %1, off offset:%2"
                 : "=v"(r) : "v"(p), "n"(IMM));
    return r;
}

#define ISSUE5(E, K, IMM)                                                       \
    do {                                                                        \
        E[0][K] = gload<IMM>(ap0); E[1][K] = gload<IMM>(ap1);                   \
        E[2][K] = gload<IMM>(ap2); E[3][K] = gload<IMM>(ap3);                   \
        E[4][K] = gload<IMM>(ap4);                                              \
    } while (0)

#define ISSUEF(E)                                                               \
    do { ISSUE5(E,0,0);    ISSUE5(E,1,256);  ISSUE5(E,2,512);  ISSUE5(E,3,768); \
         ISSUE5(E,4,1024); ISSUE5(E,5,1280); ISSUE5(E,6,1536); ISSUE5(E,7,1792);} while (0)

#define ISSUEB(E)                                                               \
    do { ISSUE5(E,0,0);     ISSUE5(E,1,-256);  ISSUE5(E,2,-512);  ISSUE5(E,3,-768); \
         ISSUE5(E,4,-1024); ISSUE5(E,5,-1280); ISSUE5(E,6,-1536); ISSUE5(E,7,-1792);} while (0)

#define SETAPF(CB)                                                              \
    do { int cb_ = (CB); if (cb_ > tf - 7) cb_ = tf - 7; if (cb_ < 0) cb_ = 0;  \
         const float* fr_ = lg + ((size_t)cb_ << 6);                            \
         ap0 = fr_ + sym[0]; ap1 = fr_ + sym[1]; ap2 = fr_ + sym[2];            \
         ap3 = fr_ + sym[3]; ap4 = fr_ + sym[4]; } while (0)

#define SETAPB(CB)                                                              \
    do { int cb_ = (CB); if (cb_ < 7) cb_ = 7; if (cb_ > tf) cb_ = tf;          \
         const float* fr_ = lg + ((size_t)cb_ << 6);                            \
         ap0 = fr_ + sym[0]; ap1 = fr_ + sym[1]; ap2 = fr_ + sym[2];            \
         ap3 = fr_ + sym[3]; ap4 = fr_ + sym[4]; } while (0)

#define WAITCNT                                                                 \
    do { asm volatile("s_waitcnt vmcnt(40)" ::: "memory");                      \
         __builtin_amdgcn_sched_barrier(0); } while (0)

#define CONV(E)                                                                 \
    do {                                                                        \
        _Pragma("unroll")                                                       \
        for (int i_ = 0; i_ < 5; ++i_) {                                        \
            _Pragma("unroll")                                                   \
            for (int k_ = 0; k_ < CH; ++k_)                                     \
                E[i_][k_] = __builtin_amdgcn_exp2f(E[i_][k_] * L2E);            \
        }                                                                       \
    } while (0)

#define PROCF(E, STEP0, MASKED)                                                 \
    do {                                                                        \
        _Pragma("unroll")                                                       \
        for (int k_ = 0; k_ < CH; ++k_) {                                       \
            double a_ = __shfl_up(p[4], 1);                                     \
            double b_ = __shfl_up(p[3], 1);                                     \
            if (lane == 0) { a_ = 0.0; b_ = 0.0; }                              \
            double e_[5];                                                       \
            _Pragma("unroll")                                                   \
            for (int i_ = 0; i_ < 5; ++i_) e_[i_] = (double)E[i_][k_];          \
            double n0_ = e_[0] * (p[0] + a_ + skd[0] * b_);                     \
            double n1_ = e_[1] * (p[1] + p[0] + skd[1] * a_);                   \
            double n2_ = e_[2] * (p[2] + p[1] + skd[2] * p[0]);                 \
            double n3_ = e_[3] * (p[3] + p[2] + skd[3] * p[1]);                 \
            double n4_ = e_[4] * (p[4] + p[3] + skd[4] * p[2]);                 \
            if (MASKED) {                                                       \
                bool act_ = ((STEP0) + k_) < nst_;                              \
                p[0] = act_ ? n0_ : p[0]; p[1] = act_ ? n1_ : p[1];             \
                p[2] = act_ ? n2_ : p[2]; p[3] = act_ ? n3_ : p[3];             \
                p[4] = act_ ? n4_ : p[4];                                       \
            } else {                                                            \
                p[0] = n0_; p[1] = n1_; p[2] = n2_; p[3] = n3_; p[4] = n4_;     \
            }                                                                   \
        }                                                                       \
    } while (0)

#define PROCB(E, STEP0, MASKED)                                                 \
    do {                                                                        \
        _Pragma("unroll")                                                       \
        for (int k_ = 0; k_ < CH; ++k_) {                                       \
            double pn0_ = __shfl_down(p[0], 1);                                 \
            double pn1_ = __shfl_down(p[1], 1);                                 \
            float en0_ = __shfl_down(E[0][k_], 1);                              \
            float en1_ = __shfl_down(E[1][k_], 1);                              \
            if (lane == 63) { pn0_ = 0.0; pn1_ = 0.0; }                         \
            double u_[5];                                                       \
            _Pragma("unroll")                                                   \
            for (int i_ = 0; i_ < 5; ++i_) u_[i_] = p[i_] * (double)E[i_][k_];  \
            double u5_ = pn0_ * (double)en0_;                                   \
            double u6_ = pn1_ * (double)en1_;                                   \
            double n0_ = u_[0] + u_[1] + skd[2] * u_[2];                        \
            double n1_ = u_[1] + u_[2] + skd[3] * u_[3];                        \
            double n2_ = u_[2] + u_[3] + skd[4] * u_[4];                        \
            double n3_ = u_[3] + u_[4] + skd[5] * u5_;                          \
            double n4_ = u_[4] + u5_ + skd[6] * u6_;                            \
            if (MASKED) {                                                       \
                bool act_ = ((STEP0) + k_) < nst_;                              \
                p[0] = act_ ? n0_ : p[0]; p[1] = act_ ? n1_ : p[1];             \
                p[2] = act_ ? n2_ : p[2]; p[3] = act_ ? n3_ : p[3];             \
                p[4] = act_ ? n4_ : p[4];                                       \
            } else {                                                            \
                p[0] = n0_; p[1] = n1_; p[2] = n2_; p[3] = n3_; p[4] = n4_;     \
            }                                                                   \
        }                                                                       \
    } while (0)

#define RENORM()                                                                \
    do {                                                                        \
        double mx_ = fmax(fmax(fmax(p[0], p[1]), fmax(p[2], p[3])), p[4]);      \
        int ex_ = (__double2hiint(mx_) >> 20) & 0x7ff;                          \
        _Pragma("unroll")                                                       \
        for (int o_ = 32; o_ >= 1; o_ >>= 1) {                                  \
            int t_ = __shfl_xor(ex_, o_);                                       \
            ex_ = t_ > ex_ ? t_ : ex_;                                          \
        }                                                                       \
        if (ex_ > 0) {                                                          \
            Cexp += ex_ - 1023;                                                 \
            double r_ = __hiloint2double((2046 - ex_) << 20, 0);                \
            _Pragma("unroll")                                                   \
            for (int i_ = 0; i_ < 5; ++i_) p[i_] *= r_;                         \
        }                                                                       \
    } while (0)

// frame-group lse reduce: group g covers frames g*4+fg (fg = lane>>4, q = lane&15)
#define LSERED(BUF, G)                                                          \
    do {                                                                        \
        int t_ = (G) * 4 + fg;                                                  \
        float m_ = fmaxf(fmaxf(BUF.x, BUF.y), fmaxf(BUF.z, BUF.w));             \
        _Pragma("unroll")                                                       \
        for (int o_ = 8; o_ >= 1; o_ >>= 1) m_ = fmaxf(m_, __shfl_xor(m_, o_)); \
        float s_ = __expf(BUF.x - m_) + __expf(BUF.y - m_) +                    \
                   __expf(BUF.z - m_) + __expf(BUF.w - m_);                     \
        _Pragma("unroll")                                                       \
        for (int o_ = 8; o_ >= 1; o_ >>= 1) s_ += __shfl_xor(s_, o_);           \
        if (q == 0 && t_ < Tb) acc += (double)(m_ + __logf(s_));                \
    } while (0)

#define LSELOAD(G)                                                              \
    ( lg4[ (size_t)( ( ((G)*4+fg) < Tb ? ((G)*4+fg) : (Tb-1) ) * 16 + q ) ] )

__global__ __launch_bounds__(384, 1) void ctc_kernel(const float* __restrict__ lgall,
                                                     const int* __restrict__ audio_len,
                                                     const int* __restrict__ labels,
                                                     float* __restrict__ out,
                                                     int B, int T, int L) {
    const int b = blockIdx.x;
    const int tid = threadIdx.x;
    const int lane = tid & 63;
    const int wid = tid >> 6;
    const int S = 2 * L + 1;
    const float* lg = lgall + (size_t)b * T * VV;

    int al = audio_len[b];
    int Tb = ((al + 128) >> 7) >> 1;
    if (Tb < 1) Tb = 1;
    if (Tb > T) Tb = T;
    const int tf = Tb - 1;
    const int mid = tf >> 1;   // fwd steps: frames 1..mid ; bwd: frames tf..mid+1

    __shared__ int lab_sh[152];
    __shared__ double beta_sh[324];
    __shared__ double lse_part[4];
    __shared__ int cexpb_sh;

    for (int k = tid; k < L; k += 384) lab_sh[k] = labels[b * L + k];
    __syncthreads();

    int cnt = 0;
    for (int k = lane; k < L; k += 64) cnt += (lab_sh[k] >= 0) ? 1 : 0;
    #pragma unroll
    for (int off = 32; off >= 1; off >>= 1) cnt += __shfl_xor(cnt, off);
    const int s_last = 2 * cnt;

    // per-state symbols (states 5*lane+i) and skip flags (i up to 6 for bwd)
    int sym[5];
    double skd[7];
    #pragma unroll
    for (int i = 0; i < 7; ++i) {
        int s = lane * 5 + i;
        int sy = 0;
        double sk = 0.0;
        if (s < S && (s & 1)) {
            int lv = lab_sh[s >> 1];
            sy = lv < 0 ? 0 : lv;
            if (s >= 3 && sy != 0) {
                int lv2 = lab_sh[(s >> 1) - 1];
                int s2 = lv2 < 0 ? 0 : lv2;
                sk = (sy != s2) ? 1.0 : 0.0;
            }
        }
        if (i < 5) sym[i] = sy;
        skd[i] = sk;
    }

    double p[5];
    int Cexp = 0;

    if (wid == 0) {
        // ---------------- forward: alpha ----------------
        #pragma unroll
        for (int i = 0; i < 5; ++i) {
            float x = lg[sym[i]];
            int s = lane * 5 + i;
            p[i] = (s <= 1) ? (double)__builtin_amdgcn_exp2f(x * L2E) : 0.0;
        }
        const int nst_ = mid;
        if (nst_ > 0) {
            const int nch = (nst_ + CH - 1) / CH;
            float eA[5][CH], eB[5][CH];
            const float *ap0, *ap1, *ap2, *ap3, *ap4;
            SETAPF(1);      ISSUEF(eA);
            SETAPF(1 + CH); ISSUEF(eB);
            int c = 0, step0 = 0, cbn = 1 + 2 * CH;
            for (;;) {
                WAITCNT; CONV(eA);
                if (c == nch - 1) { PROCF(eA, step0, 1); break; }
                PROCF(eA, step0, 0);
                SETAPF(cbn); ISSUEF(eA); cbn += CH;
                ++c; step0 += CH;
                if ((c & 3) == 0) RENORM();
                WAITCNT; CONV(eB);
                if (c == nch - 1) { PROCF(eB, step0, 1); break; }
                PROCF(eB, step0, 0);
                SETAPF(cbn); ISSUEF(eB); cbn += CH;
                ++c; step0 += CH;
                if ((c & 3) == 0) RENORM();
            }
        }
        RENORM();   // keep magnitudes safe for the dot product
    } else if (wid == 1) {
        // ---------------- backward: beta ----------------
        #pragma unroll
        for (int i = 0; i < 5; ++i) {
            int s = lane * 5 + i;
            p[i] = (s == s_last || s == s_last - 1) ? 1.0 : 0.0;
        }
        const int nst_ = tf - mid;
        if (nst_ > 0) {
            const int nch = (nst_ + CH - 1) / CH;
            float eA[5][CH], eB[5][CH];
            const float *ap0, *ap1, *ap2, *ap3, *ap4;
            SETAPB(tf);      ISSUEB(eA);
            SETAPB(tf - CH); ISSUEB(eB);
            int c = 0, step0 = 0, cbn = tf - 2 * CH;
            for (;;) {
                WAITCNT; CONV(eA);
                if (c == nch - 1) { PROCB(eA, step0, 1); break; }
                PROCB(eA, step0, 0);
                SETAPB(cbn); ISSUEB(eA); cbn -= CH;
                ++c; step0 += CH;
                if ((c & 3) == 0) RENORM();
                WAITCNT; CONV(eB);
                if (c == nch - 1) { PROCB(eB, step0, 1); break; }
                PROCB(eB, step0, 0);
                SETAPB(cbn); ISSUEB(eB); cbn -= CH;
                ++c; step0 += CH;
                if ((c & 3) == 0) RENORM();
            }
        }
        RENORM();
        #pragma unroll
        for (int i = 0; i < 5; ++i) beta_sh[lane * 5 + i] = p[i];
        if (lane == 0) cexpb_sh = Cexp;
    } else {
        // ------------- lse waves (wid 2..5): 4-way split, 4 loads in flight -------------
        const float4* lg4 = (const float4*)lg;
        const int w = wid - 2;
        const int q = lane & 15;
        const int fg = lane >> 4;
        const int ngroups = (Tb + 3) >> 2;     // groups of 4 frames
        double acc = 0.0;
        // wave w owns groups g = w, w+4, w+8, ...
        if (w < ngroups) {
            float4 b0 = LSELOAD(w);
            float4 b1 = LSELOAD(w + 4);
            float4 b2 = LSELOAD(w + 8);
            float4 b3 = LSELOAD(w + 12);
            int gcur = w, gld = w + 16;
            for (;;) {
                LSERED(b0, gcur);
                gcur += 4; if (gcur >= ngroups) break;
                b0 = LSELOAD(gld); gld += 4;
                LSERED(b1, gcur);
                gcur += 4; if (gcur >= ngroups) break;
                b1 = LSELOAD(gld); gld += 4;
                LSERED(b2, gcur);
                gcur += 4; if (gcur >= ngroups) break;
                b2 = LSELOAD(gld); gld += 4;
                LSERED(b3, gcur);
                gcur += 4; if (gcur >= ngroups) break;
                b3 = LSELOAD(gld); gld += 4;
            }
        }
        #pragma unroll
        for (int o = 32; o >= 1; o >>= 1) acc += __shfl_xor(acc, o);
        if (lane == 0) lse_part[w] = acc;
    }
    __syncthreads();

    if (wid == 0) {
        double dot = 0.0;
        #pragma unroll
        for (int i = 0; i < 5; ++i) dot += p[i] * beta_sh[lane * 5 + i];
        #pragma unroll
        for (int o = 32; o >= 1; o >>= 1) dot += __shfl_xor(dot, o);
        if (lane == 0) {
            dot = fmax(dot, 1e-290);
            double sumlse = lse_part[0] + lse_part[1] + lse_part[2] + lse_part[3];
            double lp = log(dot) + (double)(Cexp + cexpb_sh) * LN2D - sumlse;
            atomicAdd(out, (float)(-lp / (double)B));
        }
    }
}

extern "C" void kernel_launch(void* const* d_in, const int* in_sizes, int n_in,
                              void* d_out, int out_size, void* d_ws, size_t ws_size,
                              hipStream_t stream) {
    const float* logits = (const float*)d_in[0];
    const int* audio = (const int*)d_in[1];
    const int* labels = (const int*)d_in[2];
    float* out = (float*)d_out;

    int B = in_sizes[1];
    int L = in_sizes[2] / B;
    int T = in_sizes[0] / (B * VV);

    hipMemsetAsync(out, 0, sizeof(float), stream);
    ctc_kernel<<<B, 384, 0, stream>>>(logits, audio, labels, out, B, T, L);
}